// Round 5
// baseline (327.331 us; speedup 1.0000x reference)
//
#include <hip/hip_runtime.h>
#include <math.h>

// QuantumNeuralNetwork: 12-qubit, 16-layer RY+CNOT-ring state-vector sim.
// Round 5: identical dataflow to round 4 (one state per 128-thread block,
// 32 complex amps/lane as 64 named scalars, two LDS re-layouts per layer,
// CNOT-ring fused into trip 2). ONE change: pin the backend's occupancy
// target with amdgpu_waves_per_eu(4,4).
// Why: rounds 2-4 all produced VGPR_Count=64 + ~450 MB scratch traffic
// regardless of how the state was expressed (array / vector / scalars).
// __launch_bounds__(128,4) only sets MIN waves/EU; the GCN scheduler's
// memory-bound heuristic targeted 8 waves/EU (64 VGPRs) and spilled the
// state every layer. min=max=4 waves/EU -> 128-VGPR budget -> state fits.
// Layer structure (all RY gates in a layer commute):
//   L1 layout: lane t owns amp bits 11..5, reg r1 = amp bits 4..0
//     -> q7..q11 register-local; q5,q6 via quad-perm DPP (amp bits 6,5=t1,t0)
//   LDS trip 1 -> L2 layout: reg r2 = amp bits 11..7, lane owns bits 6..0
//     -> q0..q4 register-local
//   LDS trip 2 -> back to L1 FUSED with CNOT-ring permutation G (GF(2)-linear)
// Swizzle f(x)=x^(x>>6): all 4 LDS phases have rank-5 bank projections ->
// only 2-way bank aliasing (free on gfx950, m136).

#define DIM     4096
#define NLAYERS 16
#define BATCH   2048
#define NCLASS  5

// Composite CNOT-ring gather: psi_new[i] = psi_old[gperm(i)]. GF(2)-linear.
__host__ __device__ constexpr unsigned gperm(unsigned i) {
  for (int q = 11; q >= 0; --q) {
    const unsigned cbit = 1u << (11 - q);
    const unsigned tbit = 1u << (11 - ((q + 1) % 12));
    if (i & cbit) i ^= tbit;
  }
  return i;
}
__host__ __device__ constexpr unsigned swz(unsigned x) { return x ^ (x >> 6); }

// quad_perm DPP permute (VALU, no LDS): CTRL 0x4E = xor-2, 0xB1 = xor-1
template<int CTRL>
__device__ __forceinline__ float dppf(float x) {
  return __int_as_float(__builtin_amdgcn_update_dpp(
      0, __float_as_int(x), CTRL, 0xF, 0xF, true));
}

#define FOR32(M) M(0) M(1) M(2) M(3) M(4) M(5) M(6) M(7) M(8) M(9) M(10) \
  M(11) M(12) M(13) M(14) M(15) M(16) M(17) M(18) M(19) M(20) M(21) M(22) \
  M(23) M(24) M(25) M(26) M(27) M(28) M(29) M(30) M(31)

// one RY pair-rotation on registers p0,p1 (uses locals c,s in scope)
#define ROT(p0, p1) {                                        \
    const float A0 = re##p0, A1 = re##p1;                    \
    re##p0 = __builtin_fmaf(c, A0, -s * A1);                 \
    re##p1 = __builtin_fmaf(s, A0,  c * A1);                 \
    const float B0 = im##p0, B1 = im##p1;                    \
    im##p0 = __builtin_fmaf(c, B0, -s * B1);                 \
    im##p1 = __builtin_fmaf(s, B0,  c * B1); }

#define GM16 ROT(0,16) ROT(1,17) ROT(2,18) ROT(3,19) ROT(4,20) ROT(5,21) \
  ROT(6,22) ROT(7,23) ROT(8,24) ROT(9,25) ROT(10,26) ROT(11,27) ROT(12,28) \
  ROT(13,29) ROT(14,30) ROT(15,31)
#define GM8 ROT(0,8) ROT(1,9) ROT(2,10) ROT(3,11) ROT(4,12) ROT(5,13) \
  ROT(6,14) ROT(7,15) ROT(16,24) ROT(17,25) ROT(18,26) ROT(19,27) ROT(20,28) \
  ROT(21,29) ROT(22,30) ROT(23,31)
#define GM4 ROT(0,4) ROT(1,5) ROT(2,6) ROT(3,7) ROT(8,12) ROT(9,13) \
  ROT(10,14) ROT(11,15) ROT(16,20) ROT(17,21) ROT(18,22) ROT(19,23) \
  ROT(24,28) ROT(25,29) ROT(26,30) ROT(27,31)
#define GM2 ROT(0,2) ROT(1,3) ROT(4,6) ROT(5,7) ROT(8,10) ROT(9,11) \
  ROT(12,14) ROT(13,15) ROT(16,18) ROT(17,19) ROT(20,22) ROT(21,23) \
  ROT(24,26) ROT(25,27) ROT(28,30) ROT(29,31)
#define GM1 ROT(0,1) ROT(2,3) ROT(4,5) ROT(6,7) ROT(8,9) ROT(10,11) \
  ROT(12,13) ROT(14,15) ROT(16,17) ROT(18,19) ROT(20,21) ROT(22,23) \
  ROT(24,25) ROT(26,27) ROT(28,29) ROT(30,31)

__global__ __launch_bounds__(128)
__attribute__((amdgpu_waves_per_eu(4, 4)))
void qnn_sim(const float* __restrict__ zr, const float* __restrict__ zi,
             const float* __restrict__ thetas, const int* __restrict__ y,
             float* __restrict__ out) {
  __shared__ float buf[DIM];  // 16 KB: one component of the state
  const int b = blockIdx.x;
  const int t = threadIdx.x;  // 0..127

  // Layer-invariant LDS slot bases (float indices), f(x)=x^(x>>6):
  // W1  : slot = f((t<<5)|r1)    = wb1 ^ r1
  // R1/W2: slot = f((r2<<7)|t)   = rb1 ^ ((r2<<7)|(r2<<1))
  // R2  : slot = f(G((t<<5)|r1)) = rb2 ^ swz(gperm(r1))   [G,f linear]
  const int wb1 = ((t << 5) ^ (t >> 1));
  const int rb1 = (t ^ (t >> 6));
  const int Xt  = ((t << 5) ^ (t << 4)) & 0xFFF;  // G(t<<5)
  const int rb2 = (Xt ^ (Xt >> 6));

  float re0,re1,re2,re3,re4,re5,re6,re7,re8,re9,re10,re11,re12,re13,re14,re15,
        re16,re17,re18,re19,re20,re21,re22,re23,re24,re25,re26,re27,re28,re29,
        re30,re31;
  float im0,im1,im2,im3,im4,im5,im6,im7,im8,im9,im10,im11,im12,im13,im14,im15,
        im16,im17,im18,im19,im20,im21,im22,im23,im24,im25,im26,im27,im28,im29,
        im30,im31;
  {
    const float4* zr4 = (const float4*)(zr + (size_t)b * DIM + (t << 5));
    const float4* zi4 = (const float4*)(zi + (size_t)b * DIM + (t << 5));
    float4 v;
    v = zr4[0]; re0 =v.x; re1 =v.y; re2 =v.z; re3 =v.w;
    v = zr4[1]; re4 =v.x; re5 =v.y; re6 =v.z; re7 =v.w;
    v = zr4[2]; re8 =v.x; re9 =v.y; re10=v.z; re11=v.w;
    v = zr4[3]; re12=v.x; re13=v.y; re14=v.z; re15=v.w;
    v = zr4[4]; re16=v.x; re17=v.y; re18=v.z; re19=v.w;
    v = zr4[5]; re20=v.x; re21=v.y; re22=v.z; re23=v.w;
    v = zr4[6]; re24=v.x; re25=v.y; re26=v.z; re27=v.w;
    v = zr4[7]; re28=v.x; re29=v.y; re30=v.z; re31=v.w;
    v = zi4[0]; im0 =v.x; im1 =v.y; im2 =v.z; im3 =v.w;
    v = zi4[1]; im4 =v.x; im5 =v.y; im6 =v.z; im7 =v.w;
    v = zi4[2]; im8 =v.x; im9 =v.y; im10=v.z; im11=v.w;
    v = zi4[3]; im12=v.x; im13=v.y; im14=v.z; im15=v.w;
    v = zi4[4]; im16=v.x; im17=v.y; im18=v.z; im19=v.w;
    v = zi4[5]; im20=v.x; im21=v.y; im22=v.z; im23=v.w;
    v = zi4[6]; im24=v.x; im25=v.y; im26=v.z; im27=v.w;
    v = zi4[7]; im28=v.x; im29=v.y; im30=v.z; im31=v.w;
  }

#pragma unroll 1
  for (int l = 0; l < NLAYERS; ++l) {
    const float* th = thetas + l * 12;

    // ---- L1 register gates: q7..q11 (pair masks 16,8,4,2,1) ----
    { const float a = 0.5f * th[7];  const float c = __cosf(a), s = __sinf(a); GM16 }
    { const float a = 0.5f * th[8];  const float c = __cosf(a), s = __sinf(a); GM8  }
    { const float a = 0.5f * th[9];  const float c = __cosf(a), s = __sinf(a); GM4  }
    { const float a = 0.5f * th[10]; const float c = __cosf(a), s = __sinf(a); GM2  }
    { const float a = 0.5f * th[11]; const float c = __cosf(a), s = __sinf(a); GM1  }

    // ---- DPP gates: q5 (amp bit6 = t1, xor-2) ; q6 (amp bit5 = t0, xor-1)
    {
      const float a5 = 0.5f * th[5];
      const float c5 = __cosf(a5), s5 = __sinf(a5);
      const float ss5 = (t & 2) ? s5 : -s5;
#define DPP5(i) \
      re##i = __builtin_fmaf(c5, re##i, ss5 * dppf<0x4E>(re##i)); \
      im##i = __builtin_fmaf(c5, im##i, ss5 * dppf<0x4E>(im##i));
      FOR32(DPP5)
#undef DPP5
      const float a6 = 0.5f * th[6];
      const float c6 = __cosf(a6), s6 = __sinf(a6);
      const float ss6 = (t & 1) ? s6 : -s6;
#define DPP6(i) \
      re##i = __builtin_fmaf(c6, re##i, ss6 * dppf<0xB1>(re##i)); \
      im##i = __builtin_fmaf(c6, im##i, ss6 * dppf<0xB1>(im##i));
      FOR32(DPP6)
#undef DPP6
    }

    // ---- trip 1: L1 -> L2 (per component) ----
    __syncthreads();  // prev phase's reads done
#define W1R(i) buf[wb1 ^ i] = re##i;
#define R1R(i) re##i = buf[rb1 ^ ((i << 7) | (i << 1))];
#define W1I(i) buf[wb1 ^ i] = im##i;
#define R1I(i) im##i = buf[rb1 ^ ((i << 7) | (i << 1))];
    FOR32(W1R)
    __syncthreads();
    FOR32(R1R)
    __syncthreads();
    FOR32(W1I)
    __syncthreads();
    FOR32(R1I)
#undef W1R
#undef R1R
#undef W1I
#undef R1I

    // ---- L2 register gates: q0..q4 (pair masks 16,8,4,2,1) ----
    { const float a = 0.5f * th[0]; const float c = __cosf(a), s = __sinf(a); GM16 }
    { const float a = 0.5f * th[1]; const float c = __cosf(a), s = __sinf(a); GM8  }
    { const float a = 0.5f * th[2]; const float c = __cosf(a), s = __sinf(a); GM4  }
    { const float a = 0.5f * th[3]; const float c = __cosf(a), s = __sinf(a); GM2  }
    { const float a = 0.5f * th[4]; const float c = __cosf(a), s = __sinf(a); GM1  }

    // ---- trip 2: L2 -> L1 fused with CNOT-ring gather ----
    __syncthreads();
#define W2R(i) buf[rb1 ^ ((i << 7) | (i << 1))] = re##i;
#define R2R(i) re##i = buf[rb2 ^ (int)swz(gperm((unsigned)i))];
#define W2I(i) buf[rb1 ^ ((i << 7) | (i << 1))] = im##i;
#define R2I(i) im##i = buf[rb2 ^ (int)swz(gperm((unsigned)i))];
    FOR32(W2R)
    __syncthreads();
    FOR32(R2R)
    __syncthreads();
    FOR32(W2I)
    __syncthreads();
    FOR32(R2I)
#undef W2R
#undef R2R
#undef W2I
#undef R2I
  }

  // ---- Z expectations: wire w sign = amp bit (11-w) = t bit (6-w) ----
  float P = 0.f;
#define ACC(i) P += re##i * re##i + im##i * im##i;
  FOR32(ACC)
#undef ACC
  float e0 = ((t >> 6) & 1) ? -P : P;
  float e1 = ((t >> 5) & 1) ? -P : P;
  float e2 = ((t >> 4) & 1) ? -P : P;
  float e3 = ((t >> 3) & 1) ? -P : P;
  float e4 = ((t >> 2) & 1) ? -P : P;
#pragma unroll
  for (int off = 32; off >= 1; off >>= 1) {
    e0 += __shfl_xor(e0, off);
    e1 += __shfl_xor(e1, off);
    e2 += __shfl_xor(e2, off);
    e3 += __shfl_xor(e3, off);
    e4 += __shfl_xor(e4, off);
  }
  __syncthreads();  // protect buf (last R2I reads done)
  if ((t & 63) == 0) {
    const int w8 = (t >> 6) * 8;
    buf[w8 + 0] = e0; buf[w8 + 1] = e1; buf[w8 + 2] = e2;
    buf[w8 + 3] = e3; buf[w8 + 4] = e4;
  }
  __syncthreads();
  if (t == 0) {
    const float o0 = buf[0] + buf[8];
    const float o1 = buf[1] + buf[9];
    const float o2 = buf[2] + buf[10];
    const float o3 = buf[3] + buf[11];
    const float o4 = buf[4] + buf[12];
    float* op = out + 1 + (size_t)b * NCLASS;
    op[0] = o0; op[1] = o1; op[2] = o2; op[3] = o3; op[4] = o4;
    // fused NLL: loss contribution = (logsumexp(o) - o[y]) / BATCH
    const float m = fmaxf(fmaxf(fmaxf(o0, o1), fmaxf(o2, o3)), o4);
    const float sum = expf(o0 - m) + expf(o1 - m) + expf(o2 - m) +
                      expf(o3 - m) + expf(o4 - m);
    const int yb = y[b];
    const float oy = (yb == 0) ? o0 : (yb == 1) ? o1 : (yb == 2) ? o2
                   : (yb == 3) ? o3 : o4;
    const float nll = (m + logf(sum)) - oy;
    atomicAdd(out, nll * (1.0f / BATCH));
  }
}

extern "C" void kernel_launch(void* const* d_in, const int* in_sizes, int n_in,
                              void* d_out, int out_size, void* d_ws, size_t ws_size,
                              hipStream_t stream) {
  const float* zr = (const float*)d_in[0];
  const float* zi = (const float*)d_in[1];
  const float* th = (const float*)d_in[2];
  const int*   y  = (const int*)d_in[3];
  float* out = (float*)d_out;
  hipMemsetAsync(out, 0, sizeof(float), stream);  // zero loss accumulator
  qnn_sim<<<BATCH, 128, 0, stream>>>(zr, zi, th, y, out);
}

// Round 6
// 273.116 us; speedup vs baseline: 1.1985x; 1.1985x over previous
//
#include <hip/hip_runtime.h>
#include <math.h>

// QuantumNeuralNetwork: 12-qubit, 16-layer RY+CNOT-ring state-vector sim.
// Round 6: rounds 2-5 proved the backend pins this kernel at 64 VGPRs no
// matter what (array/vector/scalars, launch_bounds, waves_per_eu) and spills
// the 64-reg state (~500 MB scratch traffic = the whole runtime). So: design
// INSIDE the 64-VGPR cap. 256 threads/block, 16 complex amps/lane = 32 state
// VGPRs + ~20 temps. Spilling becomes impossible instead of discouraged.
// Layer structure (RY gates on distinct qubits commute):
//   L1 layout: amp = (t<<4)|r  (t: 8 bits, r: amp bits 3..0)
//     q8..q11 register-local (r masks 8,4,2,1)
//     q7 (amp bit4 = t0): DPP quad_perm xor1 (0xB1)
//     q6 (amp bit5 = t1): DPP quad_perm xor2 (0x4E)
//     q5 (amp bit6 = t2): ds_swizzle xor4 (0x101F)
//     q4 (amp bit7 = t3): ds_swizzle xor8 (0x201F)
//   LDS trip 1 -> L2 layout: amp = (r2<<8)|t -> q0..q3 register-local
//   LDS trip 2 -> back to L1 FUSED with CNOT-ring perm G (GF(2)-linear).
// Swizzle f(x)=x^(x>>6): all 4 LDS phases have rank-5 bank projections over
// the 6 lane bits -> exactly 2-way bank aliasing (free on gfx950, m136).

#define DIM     4096
#define NLAYERS 16
#define BATCH   2048
#define NCLASS  5

// Composite CNOT-ring gather: psi_new[i] = psi_old[gperm(i)]. GF(2)-linear.
__host__ __device__ constexpr unsigned gperm(unsigned i) {
  for (int q = 11; q >= 0; --q) {
    const unsigned cbit = 1u << (11 - q);
    const unsigned tbit = 1u << (11 - ((q + 1) % 12));
    if (i & cbit) i ^= tbit;
  }
  return i;
}
__host__ __device__ constexpr unsigned swz(unsigned x) { return x ^ (x >> 6); }

// quad_perm DPP permute (VALU): CTRL 0x4E = xor-2, 0xB1 = xor-1
template<int CTRL>
__device__ __forceinline__ float dppf(float x) {
  return __int_as_float(__builtin_amdgcn_update_dpp(
      0, __float_as_int(x), CTRL, 0xF, 0xF, true));
}
// ds_swizzle lane-xor permute (LDS pipe, no barrier, conflict-free)
template<int PAT>
__device__ __forceinline__ float swzf(float x) {
  return __int_as_float(__builtin_amdgcn_ds_swizzle(__float_as_int(x), PAT));
}

#define FOR16(M) M(0) M(1) M(2) M(3) M(4) M(5) M(6) M(7) M(8) M(9) M(10) \
  M(11) M(12) M(13) M(14) M(15)

// one RY pair-rotation on registers p0,p1 (uses locals c,s in scope)
#define ROT(p0, p1) {                                        \
    const float A0 = re##p0, A1 = re##p1;                    \
    re##p0 = __builtin_fmaf(c, A0, -s * A1);                 \
    re##p1 = __builtin_fmaf(s, A0,  c * A1);                 \
    const float B0 = im##p0, B1 = im##p1;                    \
    im##p0 = __builtin_fmaf(c, B0, -s * B1);                 \
    im##p1 = __builtin_fmaf(s, B0,  c * B1); }

#define GM8 ROT(0,8) ROT(1,9) ROT(2,10) ROT(3,11) ROT(4,12) ROT(5,13) \
  ROT(6,14) ROT(7,15)
#define GM4 ROT(0,4) ROT(1,5) ROT(2,6) ROT(3,7) ROT(8,12) ROT(9,13) \
  ROT(10,14) ROT(11,15)
#define GM2 ROT(0,2) ROT(1,3) ROT(4,6) ROT(5,7) ROT(8,10) ROT(9,11) \
  ROT(12,14) ROT(13,15)
#define GM1 ROT(0,1) ROT(2,3) ROT(4,5) ROT(6,7) ROT(8,9) ROT(10,11) \
  ROT(12,13) ROT(14,15)

// lane-xor gate: new = c*me + (own amp bit ? +s : -s) * partner
#define XGATE_DPP(CTRL, SS) \
  { FOR16(XG1) } struct _dummy##CTRL
#define DO_DPP(CTRL, ss) \
  do { \
    _Pragma("unroll") \
    for (int _z = 0; _z < 1; ++_z) {} \
  } while (0)

__global__ __launch_bounds__(256)
void qnn_sim(const float* __restrict__ zr, const float* __restrict__ zi,
             const float* __restrict__ thetas, const int* __restrict__ y,
             float* __restrict__ out) {
  __shared__ float buf[DIM];  // 16 KB: one component of the state
  const int b = blockIdx.x;
  const int t = threadIdx.x;  // 0..255

  // Layer-invariant LDS slot bases (float word indices), f(x)=x^(x>>6):
  // W1  : slot = f((t<<4)|r)    = wb1 ^ r            (r<16 -> f(r)=r)
  // R1/W2: slot = f((r2<<8)|t)  = rb1 ^ ((r2<<8)^(r2<<2))
  // R2  : slot = f(G((t<<4)|r)) = rb2 ^ swz(gperm(r))  [G,f linear]
  const int wb1 = ((t << 4) ^ (t >> 2));
  const int rb1 = (t ^ (t >> 6));
  const int Xt  = ((t << 4) ^ (t << 3));  // G(t<<4), 12 bits
  const int rb2 = (Xt ^ (Xt >> 6));

  float re0,re1,re2,re3,re4,re5,re6,re7,re8,re9,re10,re11,re12,re13,re14,re15;
  float im0,im1,im2,im3,im4,im5,im6,im7,im8,im9,im10,im11,im12,im13,im14,im15;
  {
    const float4* zr4 = (const float4*)(zr + (size_t)b * DIM + (t << 4));
    const float4* zi4 = (const float4*)(zi + (size_t)b * DIM + (t << 4));
    float4 v;
    v = zr4[0]; re0 =v.x; re1 =v.y; re2 =v.z; re3 =v.w;
    v = zr4[1]; re4 =v.x; re5 =v.y; re6 =v.z; re7 =v.w;
    v = zr4[2]; re8 =v.x; re9 =v.y; re10=v.z; re11=v.w;
    v = zr4[3]; re12=v.x; re13=v.y; re14=v.z; re15=v.w;
    v = zi4[0]; im0 =v.x; im1 =v.y; im2 =v.z; im3 =v.w;
    v = zi4[1]; im4 =v.x; im5 =v.y; im6 =v.z; im7 =v.w;
    v = zi4[2]; im8 =v.x; im9 =v.y; im10=v.z; im11=v.w;
    v = zi4[3]; im12=v.x; im13=v.y; im14=v.z; im15=v.w;
  }

#pragma unroll 1
  for (int l = 0; l < NLAYERS; ++l) {
    const float* th = thetas + l * 12;

    // ---- L1 register gates: q8..q11 (amp bits 3..0 -> masks 8,4,2,1) ----
    { const float a = 0.5f * th[8];  const float c = __cosf(a), s = __sinf(a); GM8 }
    { const float a = 0.5f * th[9];  const float c = __cosf(a), s = __sinf(a); GM4 }
    { const float a = 0.5f * th[10]; const float c = __cosf(a), s = __sinf(a); GM2 }
    { const float a = 0.5f * th[11]; const float c = __cosf(a), s = __sinf(a); GM1 }

    // ---- DPP gates: q7 (amp bit4 = t0, xor1), q6 (amp bit5 = t1, xor2) ----
    {
      const float a7 = 0.5f * th[7];
      const float c7 = __cosf(a7), s7 = __sinf(a7);
      const float ss7 = (t & 1) ? s7 : -s7;
#define DPPG7(i) \
      re##i = __builtin_fmaf(c7, re##i, ss7 * dppf<0xB1>(re##i)); \
      im##i = __builtin_fmaf(c7, im##i, ss7 * dppf<0xB1>(im##i));
      FOR16(DPPG7)
#undef DPPG7
      const float a6 = 0.5f * th[6];
      const float c6 = __cosf(a6), s6 = __sinf(a6);
      const float ss6 = (t & 2) ? s6 : -s6;
#define DPPG6(i) \
      re##i = __builtin_fmaf(c6, re##i, ss6 * dppf<0x4E>(re##i)); \
      im##i = __builtin_fmaf(c6, im##i, ss6 * dppf<0x4E>(im##i));
      FOR16(DPPG6)
#undef DPPG6
    }

    // ---- swizzle gates: q5 (amp bit6 = t2, xor4), q4 (amp bit7 = t3, xor8)
    {
      const float a5 = 0.5f * th[5];
      const float c5 = __cosf(a5), s5 = __sinf(a5);
      const float ss5 = (t & 4) ? s5 : -s5;
#define SWG5(i) \
      re##i = __builtin_fmaf(c5, re##i, ss5 * swzf<0x101F>(re##i)); \
      im##i = __builtin_fmaf(c5, im##i, ss5 * swzf<0x101F>(im##i));
      FOR16(SWG5)
#undef SWG5
      const float a4 = 0.5f * th[4];
      const float c4 = __cosf(a4), s4 = __sinf(a4);
      const float ss4 = (t & 8) ? s4 : -s4;
#define SWG4(i) \
      re##i = __builtin_fmaf(c4, re##i, ss4 * swzf<0x201F>(re##i)); \
      im##i = __builtin_fmaf(c4, im##i, ss4 * swzf<0x201F>(im##i));
      FOR16(SWG4)
#undef SWG4
    }

    // ---- trip 1: L1 -> L2 (per component) ----
    __syncthreads();  // prev layer's R2 reads done
#define W1R(i) buf[wb1 ^ i] = re##i;
#define R1R(i) re##i = buf[rb1 ^ ((i << 8) ^ (i << 2))];
#define W1I(i) buf[wb1 ^ i] = im##i;
#define R1I(i) im##i = buf[rb1 ^ ((i << 8) ^ (i << 2))];
    FOR16(W1R)
    __syncthreads();
    FOR16(R1R)
    __syncthreads();
    FOR16(W1I)
    __syncthreads();
    FOR16(R1I)
#undef W1R
#undef R1R
#undef W1I
#undef R1I

    // ---- L2 register gates: q0..q3 (amp bits 11..8 -> masks 8,4,2,1) ----
    { const float a = 0.5f * th[0]; const float c = __cosf(a), s = __sinf(a); GM8 }
    { const float a = 0.5f * th[1]; const float c = __cosf(a), s = __sinf(a); GM4 }
    { const float a = 0.5f * th[2]; const float c = __cosf(a), s = __sinf(a); GM2 }
    { const float a = 0.5f * th[3]; const float c = __cosf(a), s = __sinf(a); GM1 }

    // ---- trip 2: L2 -> L1 fused with CNOT-ring gather ----
    __syncthreads();
#define W2R(i) buf[rb1 ^ ((i << 8) ^ (i << 2))] = re##i;
#define R2R(i) re##i = buf[rb2 ^ (int)swz(gperm((unsigned)i))];
#define W2I(i) buf[rb1 ^ ((i << 8) ^ (i << 2))] = im##i;
#define R2I(i) im##i = buf[rb2 ^ (int)swz(gperm((unsigned)i))];
    FOR16(W2R)
    __syncthreads();
    FOR16(R2R)
    __syncthreads();
    FOR16(W2I)
    __syncthreads();
    FOR16(R2I)
#undef W2R
#undef R2R
#undef W2I
#undef R2I
  }

  // ---- Z expectations: wire w sign = amp bit (11-w) = t bit (7-w) ----
  float P = 0.f;
#define ACC(i) P += re##i * re##i + im##i * im##i;
  FOR16(ACC)
#undef ACC
  float e0 = ((t >> 7) & 1) ? -P : P;
  float e1 = ((t >> 6) & 1) ? -P : P;
  float e2 = ((t >> 5) & 1) ? -P : P;
  float e3 = ((t >> 4) & 1) ? -P : P;
  float e4 = ((t >> 3) & 1) ? -P : P;
#pragma unroll
  for (int off = 32; off >= 1; off >>= 1) {
    e0 += __shfl_xor(e0, off);
    e1 += __shfl_xor(e1, off);
    e2 += __shfl_xor(e2, off);
    e3 += __shfl_xor(e3, off);
    e4 += __shfl_xor(e4, off);
  }
  __syncthreads();  // protect buf (last R2I reads done)
  if ((t & 63) == 0) {
    const int w8 = (t >> 6) * 8;
    buf[w8 + 0] = e0; buf[w8 + 1] = e1; buf[w8 + 2] = e2;
    buf[w8 + 3] = e3; buf[w8 + 4] = e4;
  }
  __syncthreads();
  if (t == 0) {
    const float o0 = buf[0] + buf[8]  + buf[16] + buf[24];
    const float o1 = buf[1] + buf[9]  + buf[17] + buf[25];
    const float o2 = buf[2] + buf[10] + buf[18] + buf[26];
    const float o3 = buf[3] + buf[11] + buf[19] + buf[27];
    const float o4 = buf[4] + buf[12] + buf[20] + buf[28];
    float* op = out + 1 + (size_t)b * NCLASS;
    op[0] = o0; op[1] = o1; op[2] = o2; op[3] = o3; op[4] = o4;
    // fused NLL: loss contribution = (logsumexp(o) - o[y]) / BATCH
    const float m = fmaxf(fmaxf(fmaxf(o0, o1), fmaxf(o2, o3)), o4);
    const float sum = expf(o0 - m) + expf(o1 - m) + expf(o2 - m) +
                      expf(o3 - m) + expf(o4 - m);
    const int yb = y[b];
    const float oy = (yb == 0) ? o0 : (yb == 1) ? o1 : (yb == 2) ? o2
                   : (yb == 3) ? o3 : o4;
    const float nll = (m + logf(sum)) - oy;
    atomicAdd(out, nll * (1.0f / BATCH));
  }
}

extern "C" void kernel_launch(void* const* d_in, const int* in_sizes, int n_in,
                              void* d_out, int out_size, void* d_ws, size_t ws_size,
                              hipStream_t stream) {
  const float* zr = (const float*)d_in[0];
  const float* zi = (const float*)d_in[1];
  const float* th = (const float*)d_in[2];
  const int*   y  = (const int*)d_in[3];
  float* out = (float*)d_out;
  hipMemsetAsync(out, 0, sizeof(float), stream);  // zero loss accumulator
  qnn_sim<<<BATCH, 256, 0, stream>>>(zr, zi, th, y, out);
}